// Round 2
// baseline (1016.305 us; speedup 1.0000x reference)
//
#include <hip/hip_runtime.h>
#include <hip/hip_bf16.h>

// 2-layer GCN + CORAL head.
// Pipeline:
//  1. detect edge_index width (int32 vs int64) on device
//  2. histogram in-degree  (atomicAdd, 1.6M edges)
//  3. deg_inv_sqrt
//  4. exclusive prefix scan of counts -> CSR row_ptr (3-kernel scan)
//  5. counting-sort fill: sorted_src grouped by dst
//  6. GEMM h = x @ W1   (LDS W-half, 8-row register blocking, readlane bcast)
//  7. pull-aggregate (atomic-free): out = relu(b + d_n*(d_n*h_n + sum d_s*h_s))
//  8. GEMM h2 = h @ W2
//  9. pull-aggregate + fused CORAL head: logits = (h2 . w_fc) + th_bias

#define FEAT 128

// ---------------- mode detect ----------------
__global__ void detect_mode(const int* __restrict__ p, int* __restrict__ flag) {
    // If data is int64, the high word of every value (<2^31) is 0.
    int t = threadIdx.x;                 // 64 threads, one wave
    int v = p[2 * t + 1];
    unsigned long long b = __ballot(v != 0);
    if (t == 0) flag[0] = (b == 0ull) ? 1 : 0;   // 1 => int64 layout
}

// ---------------- degree histogram ----------------
__global__ void count_deg(const int* __restrict__ p, const int* __restrict__ flag,
                          int* __restrict__ cnt, int E) {
    int i = blockIdx.x * blockDim.x + threadIdx.x;
    if (i >= E) return;
    int m = flag[0];
    int d = m ? p[2 * ((size_t)E + i)] : p[(size_t)E + i];
    atomicAdd(&cnt[d], 1);
}

__global__ void calc_dis(const int* __restrict__ cnt, float* __restrict__ dis, int n) {
    int i = blockIdx.x * blockDim.x + threadIdx.x;
    if (i < n) dis[i] = 1.0f / sqrtf((float)cnt[i] + 1.0f);
}

// ---------------- 3-kernel exclusive scan (2048 elems / block) ----------------
__global__ void scan1(const int* __restrict__ cnt, int* __restrict__ out,
                      int* __restrict__ bsum, int n) {
    __shared__ int tmp[256];
    int base = blockIdx.x * 2048;
    int idx = base + threadIdx.x * 8;
    int v[8]; int s = 0;
#pragma unroll
    for (int i = 0; i < 8; ++i) { int id = idx + i; v[i] = (id < n) ? cnt[id] : 0; s += v[i]; }
    tmp[threadIdx.x] = s;
    __syncthreads();
    for (int off = 1; off < 256; off <<= 1) {
        int t = (threadIdx.x >= (unsigned)off) ? tmp[threadIdx.x - off] : 0;
        __syncthreads();
        tmp[threadIdx.x] += t;
        __syncthreads();
    }
    int excl = (threadIdx.x == 0) ? 0 : tmp[threadIdx.x - 1];
    if (threadIdx.x == 255) bsum[blockIdx.x] = tmp[255];
    int run = excl;
#pragma unroll
    for (int i = 0; i < 8; ++i) { int id = idx + i; if (id < n) out[id] = run; run += v[i]; }
}

__global__ void scan2(int* __restrict__ bsum, int nb) {
    __shared__ int tmp[256];
    int v = (threadIdx.x < (unsigned)nb) ? bsum[threadIdx.x] : 0;
    tmp[threadIdx.x] = v;
    __syncthreads();
    for (int off = 1; off < 256; off <<= 1) {
        int t = (threadIdx.x >= (unsigned)off) ? tmp[threadIdx.x - off] : 0;
        __syncthreads();
        tmp[threadIdx.x] += t;
        __syncthreads();
    }
    int excl = (threadIdx.x == 0) ? 0 : tmp[threadIdx.x - 1];
    if (threadIdx.x < (unsigned)nb) bsum[threadIdx.x] = excl;
}

__global__ void scan3(int* __restrict__ out, int* __restrict__ cursor,
                      const int* __restrict__ bsum, int n) {
    int i = blockIdx.x * blockDim.x + threadIdx.x;
    if (i < n) {
        int v = out[i] + bsum[i >> 11];
        out[i] = v;
        cursor[i] = v;
    }
}

// ---------------- counting-sort fill ----------------
__global__ void fill_sorted(const int* __restrict__ p, const int* __restrict__ flag,
                            int* __restrict__ cursor, int* __restrict__ ssrc, int E) {
    int i = blockIdx.x * blockDim.x + threadIdx.x;
    if (i >= E) return;
    int m = flag[0];
    int s, d;
    if (m) { s = p[2 * (size_t)i]; d = p[2 * ((size_t)E + i)]; }
    else   { s = p[(size_t)i];     d = p[(size_t)E + i]; }
    int pos = atomicAdd(&cursor[d], 1);
    ssrc[pos] = s;
}

// ---------------- GEMM: Y[n][128] = X[n][128] @ W[128][128] ----------------
// Block = 256 threads (4 waves). blockIdx.x&1 selects a 64-col half of W
// staged in LDS (32 KB). Each wave owns 8 rows; x rows live in registers
// (float2/lane); x[r][k] broadcast via v_readlane (compile-time lane index).
// Per 8-row group: 128 conflict-free ds_read_b32 vs 2048 VALU ops -> VALU-bound.
__global__ __launch_bounds__(256) void gemm128(const float* __restrict__ X,
                                               const float* __restrict__ W,
                                               float* __restrict__ Y, int n) {
    __shared__ float Wl[128 * 64];     // [k][64 cols]
    const int c0 = (blockIdx.x & 1) * 64;
    for (int i = threadIdx.x; i < 128 * 16; i += 256) {
        int k = i >> 4, q = i & 15;
        ((float4*)(Wl + k * 64))[q] = *(const float4*)(W + k * 128 + c0 + q * 4);
    }
    __syncthreads();
    const int wave = threadIdx.x >> 6, lane = threadIdx.x & 63;
    const int r0 = (int)(blockIdx.x >> 1) * 32 + wave * 8;
    if (r0 >= n) return;

    float2 xr[8];
#pragma unroll
    for (int r = 0; r < 8; ++r)
        if (r0 + r < n) xr[r] = ((const float2*)(X + (size_t)(r0 + r) * FEAT))[lane];

    float acc[8];
#pragma unroll
    for (int r = 0; r < 8; ++r) acc[r] = 0.f;

    const float* wp = Wl + lane;
#pragma unroll
    for (int k = 0; k < 128; ++k) {
        float w = wp[k * 64];
        const int srcLane = k >> 1;
#pragma unroll
        for (int r = 0; r < 8; ++r) {
            float xv = (k & 1) ? xr[r].y : xr[r].x;
            float xb = __int_as_float(
                __builtin_amdgcn_readlane(__float_as_int(xv), srcLane));
            acc[r] = fmaf(xb, w, acc[r]);
        }
    }
#pragma unroll
    for (int r = 0; r < 8; ++r)
        if (r0 + r < n) Y[(size_t)(r0 + r) * FEAT + c0 + lane] = acc[r];
}

// ---------------- pull aggregate (+ optional fused CORAL head) ----------------
template <bool HEAD>
__global__ __launch_bounds__(256) void agg_kernel(
    const float* __restrict__ H, const int* __restrict__ row_ptr,
    const int* __restrict__ cnt, const int* __restrict__ ssrc,
    const float* __restrict__ dis, const float* __restrict__ bias,
    float* __restrict__ O, const float* __restrict__ wfc,
    const float* __restrict__ thb, int n) {
    const int wave = threadIdx.x >> 6, lane = threadIdx.x & 63;
    int node = blockIdx.x * 4 + wave;
    if (node >= n) return;
    float dn = dis[node];
    int beg = row_ptr[node];
    int end = beg + cnt[node];
    float2 hv = ((const float2*)(H + (size_t)node * FEAT))[lane];
    float ax = dn * hv.x, ay = dn * hv.y;
    for (int j = beg; j < end; ++j) {
        int s = ssrc[j];
        float w = dis[s];
        float2 m = ((const float2*)(H + (size_t)s * FEAT))[lane];
        ax = fmaf(w, m.x, ax);
        ay = fmaf(w, m.y, ay);
    }
    float2 bv = ((const float2*)bias)[lane];
    float o0 = fmaxf(fmaf(dn, ax, bv.x), 0.f);
    float o1 = fmaxf(fmaf(dn, ay, bv.y), 0.f);
    if (!HEAD) {
        ((float2*)(O + (size_t)node * FEAT))[lane] = make_float2(o0, o1);
    } else {
        float2 wv = ((const float2*)wfc)[lane];
        float part = fmaf(o0, wv.x, o1 * wv.y);
#pragma unroll
        for (int m_ = 32; m_ >= 1; m_ >>= 1) part += __shfl_xor(part, m_, 64);
        if (lane < 4) O[(size_t)node * 4 + lane] = part + thb[lane];
    }
}

extern "C" void kernel_launch(void* const* d_in, const int* in_sizes, int n_in,
                              void* d_out, int out_size, void* d_ws, size_t ws_size,
                              hipStream_t stream) {
    const float* x   = (const float*)d_in[0];
    const int*   ei  = (const int*)d_in[1];
    const float* W1  = (const float*)d_in[2];
    const float* b1  = (const float*)d_in[3];
    const float* W2  = (const float*)d_in[4];
    const float* b2  = (const float*)d_in[5];
    const float* wfc = (const float*)d_in[6];
    const float* thb = (const float*)d_in[7];
    const int N = in_sizes[0] / FEAT;
    const int E = in_sizes[1] / 2;
    float* out = (float*)d_out;

    char* w = (char*)d_ws;
    int*   flag = (int*)w;                       // [1]
    int*   bsum = (int*)(w + 256);               // [<=256]
    int*   deg  = (int*)(w + 2048);              // [N]
    int*   rowp = deg + N;                       // [N]
    int*   curs = rowp + N;                      // [N]
    float* dis  = (float*)(curs + N);            // [N]
    int*   ssrc = (int*)(dis + N);               // [E]
    size_t off  = (((char*)(ssrc + E)) - w + 511) & ~(size_t)511;
    float* hA   = (float*)(w + off);             // [N*128]
    float* hB   = hA + (size_t)N * FEAT;         // [N*128]

    hipMemsetAsync(deg, 0, (size_t)N * 4, stream);
    detect_mode<<<1, 64, 0, stream>>>(ei, flag);
    count_deg<<<(E + 255) / 256, 256, 0, stream>>>(ei, flag, deg, E);
    calc_dis<<<(N + 255) / 256, 256, 0, stream>>>(deg, dis, N);
    const int NB = (N + 2047) / 2048;
    scan1<<<NB, 256, 0, stream>>>(deg, rowp, bsum, N);
    scan2<<<1, 256, 0, stream>>>(bsum, NB);
    scan3<<<(N + 255) / 256, 256, 0, stream>>>(rowp, curs, bsum, N);
    fill_sorted<<<(E + 255) / 256, 256, 0, stream>>>(ei, flag, curs, ssrc, E);

    const int gemm_blocks = 2 * ((N + 31) / 32);
    gemm128<<<gemm_blocks, 256, 0, stream>>>(x, W1, hA, N);
    agg_kernel<false><<<(N + 3) / 4, 256, 0, stream>>>(hA, rowp, deg, ssrc, dis, b1,
                                                       hB, nullptr, nullptr, N);
    gemm128<<<gemm_blocks, 256, 0, stream>>>(hB, W2, hA, N);
    agg_kernel<true><<<(N + 3) / 4, 256, 0, stream>>>(hA, rowp, deg, ssrc, dis, b2,
                                                      out, wfc, thb, N);
}

// Round 4
// 616.603 us; speedup vs baseline: 1.6482x; 1.6482x over previous
//
#include <hip/hip_runtime.h>
#include <hip/hip_bf16.h>

// 2-layer GCN + CORAL head, MFMA edition.
//  - split-bf16 (hi/lo) MFMA GEMM: x@W = (xh+xl)@(wh+wl), 4 products, fp32 acc
//  - GEMM epilogue pre-scales row r by deg_inv_sqrt[r]  => agg loop is pure add
//  - pull-model aggregation over counting-sorted CSR (atomic-free), unroll x8
//  - layer-1 agg epilogue fuses relu + bf16 hi/lo conversion for layer-2 GEMM
//  - layer-2 agg fuses relu + CORAL head (dot w_fc + th_bias)

#define FEAT 128
typedef unsigned short u16;
typedef __attribute__((ext_vector_type(8))) short bf16x8;
typedef __attribute__((ext_vector_type(4))) float f32x4;
#define MFMA16 __builtin_amdgcn_mfma_f32_16x16x32_bf16

__device__ inline u16 f2bf(float f) {
    __hip_bfloat16 b = __float2bfloat16(f);
    return __builtin_bit_cast(u16, b);
}
__device__ inline float bf2f(u16 u) {
    __hip_bfloat16 b = __builtin_bit_cast(__hip_bfloat16, u);
    return __bfloat162float(b);
}

// ---------------- mode detect (int64 vs int32 edge_index) ----------------
__global__ void detect_mode(const int* __restrict__ p, int* __restrict__ flag) {
    int t = threadIdx.x;
    int v = p[2 * t + 1];
    unsigned long long b = __ballot(v != 0);
    if (t == 0) flag[0] = (b == 0ull) ? 1 : 0;
}

// ---------------- degree histogram ----------------
__global__ void count_deg(const int* __restrict__ p, const int* __restrict__ flag,
                          int* __restrict__ cnt, int E) {
    int i = blockIdx.x * blockDim.x + threadIdx.x;
    if (i >= E) return;
    int m = flag[0];
    int d = m ? p[2 * ((size_t)E + i)] : p[(size_t)E + i];
    atomicAdd(&cnt[d], 1);
}

__global__ void calc_dis(const int* __restrict__ cnt, float* __restrict__ dis, int n) {
    int i = blockIdx.x * blockDim.x + threadIdx.x;
    if (i < n) dis[i] = 1.0f / sqrtf((float)cnt[i] + 1.0f);
}

// ---------------- 3-kernel exclusive scan ----------------
__global__ void scan1(const int* __restrict__ cnt, int* __restrict__ out,
                      int* __restrict__ bsum, int n) {
    __shared__ int tmp[256];
    int base = blockIdx.x * 2048;
    int idx = base + threadIdx.x * 8;
    int v[8]; int s = 0;
#pragma unroll
    for (int i = 0; i < 8; ++i) { int id = idx + i; v[i] = (id < n) ? cnt[id] : 0; s += v[i]; }
    tmp[threadIdx.x] = s;
    __syncthreads();
    for (int off = 1; off < 256; off <<= 1) {
        int t = (threadIdx.x >= (unsigned)off) ? tmp[threadIdx.x - off] : 0;
        __syncthreads();
        tmp[threadIdx.x] += t;
        __syncthreads();
    }
    int excl = (threadIdx.x == 0) ? 0 : tmp[threadIdx.x - 1];
    if (threadIdx.x == 255) bsum[blockIdx.x] = tmp[255];
    int run = excl;
#pragma unroll
    for (int i = 0; i < 8; ++i) { int id = idx + i; if (id < n) out[id] = run; run += v[i]; }
}

__global__ void scan2(int* __restrict__ bsum, int nb) {
    __shared__ int tmp[256];
    int v = (threadIdx.x < (unsigned)nb) ? bsum[threadIdx.x] : 0;
    tmp[threadIdx.x] = v;
    __syncthreads();
    for (int off = 1; off < 256; off <<= 1) {
        int t = (threadIdx.x >= (unsigned)off) ? tmp[threadIdx.x - off] : 0;
        __syncthreads();
        tmp[threadIdx.x] += t;
        __syncthreads();
    }
    int excl = (threadIdx.x == 0) ? 0 : tmp[threadIdx.x - 1];
    if (threadIdx.x < (unsigned)nb) bsum[threadIdx.x] = excl;
}

__global__ void scan3(int* __restrict__ out, int* __restrict__ cursor,
                      const int* __restrict__ bsum, int n) {
    int i = blockIdx.x * blockDim.x + threadIdx.x;
    if (i < n) {
        int v = out[i] + bsum[i >> 11];
        out[i] = v;
        cursor[i] = v;
    }
}

// ---------------- counting-sort fill ----------------
__global__ void fill_sorted(const int* __restrict__ p, const int* __restrict__ flag,
                            int* __restrict__ cursor, int* __restrict__ ssrc, int E) {
    int i = blockIdx.x * blockDim.x + threadIdx.x;
    if (i >= E) return;
    int m = flag[0];
    int s, d;
    if (m) { s = p[2 * (size_t)i]; d = p[2 * ((size_t)E + i)]; }
    else   { s = p[(size_t)i];     d = p[(size_t)E + i]; }
    int pos = atomicAdd(&cursor[d], 1);
    ssrc[pos] = s;
}

// ---------------- fp32 -> bf16 hi/lo split ----------------
__global__ void conv_x(const float* __restrict__ x, u16* __restrict__ hi,
                       u16* __restrict__ lo, int n4) {
    int i = blockIdx.x * blockDim.x + threadIdx.x;
    if (i >= n4) return;
    float4 v = ((const float4*)x)[i];
    ushort4 h, l;
    h.x = f2bf(v.x); l.x = f2bf(v.x - bf2f(h.x));
    h.y = f2bf(v.y); l.y = f2bf(v.y - bf2f(h.y));
    h.z = f2bf(v.z); l.z = f2bf(v.z - bf2f(h.z));
    h.w = f2bf(v.w); l.w = f2bf(v.w - bf2f(h.w));
    ((ushort4*)hi)[i] = h;
    ((ushort4*)lo)[i] = l;
}

// W [k][col] fp32 -> transposed bf16 hi/lo Wt[col][k]
__global__ void conv_w(const float* __restrict__ W, u16* __restrict__ th,
                       u16* __restrict__ tl) {
    int idx = blockIdx.x * 256 + threadIdx.x;   // 16384
    int k = idx >> 7, col = idx & 127;
    float v = W[idx];
    u16 h = f2bf(v);
    u16 l = f2bf(v - bf2f(h));
    th[col * 128 + k] = h;
    tl[col * 128 + k] = l;
}

// ---------------- MFMA GEMM: Y[r][c] = dis[r] * sum_k X[r][k] W[k][c] ----------
// X given as bf16 hi/lo [N][128]; W given transposed bf16 hi/lo [col][128].
// Block = 4 waves; wave owns 32 cols (2 col-tiles, B frags resident in VGPRs);
// grid-strides over 16-row tiles. 16 MFMAs (4 k-chunks x 4 hi/lo products)
// per col-tile per row-tile.
__global__ __launch_bounds__(256) void gemm_mfma(
    const u16* __restrict__ Xhi, const u16* __restrict__ Xlo,
    const u16* __restrict__ Whi, const u16* __restrict__ Wlo,
    const float* __restrict__ dis, float* __restrict__ Y, int n, int nt) {
    const int wave = threadIdx.x >> 6, lane = threadIdx.x & 63;
    const int l15 = lane & 15, hi4 = lane >> 4;

    bf16x8 bh[2][4], bl[2][4];
#pragma unroll
    for (int ct = 0; ct < 2; ++ct) {
        const int col = wave * 32 + ct * 16 + l15;
#pragma unroll
        for (int j = 0; j < 4; ++j) {
            const int off = col * 128 + j * 32 + hi4 * 8;
            bh[ct][j] = *(const bf16x8*)(Whi + off);
            bl[ct][j] = *(const bf16x8*)(Wlo + off);
        }
    }

    for (int rt = blockIdx.x; rt < nt; rt += gridDim.x) {
        const int r0 = rt * 16;
        const int row = min(r0 + l15, n - 1);
        bf16x8 ah[4], al[4];
#pragma unroll
        for (int j = 0; j < 4; ++j) {
            const size_t off = (size_t)row * 128 + j * 32 + hi4 * 8;
            ah[j] = *(const bf16x8*)(Xhi + off);
            al[j] = *(const bf16x8*)(Xlo + off);
        }
#pragma unroll
        for (int ct = 0; ct < 2; ++ct) {
            f32x4 a = {0.f, 0.f, 0.f, 0.f};
#pragma unroll
            for (int j = 0; j < 4; ++j) {
                a = MFMA16(ah[j], bh[ct][j], a, 0, 0, 0);
                a = MFMA16(al[j], bh[ct][j], a, 0, 0, 0);
                a = MFMA16(ah[j], bl[ct][j], a, 0, 0, 0);
                a = MFMA16(al[j], bl[ct][j], a, 0, 0, 0);
            }
            const int c0 = wave * 32 + ct * 16 + l15;
#pragma unroll
            for (int q = 0; q < 4; ++q) {
                const int r = r0 + hi4 * 4 + q;
                if (r < n) Y[(size_t)r * FEAT + c0] = a[q] * dis[r];
            }
        }
    }
}

// ---------------- pull aggregate ----------------
// H rows are pre-scaled by dis[row]; inner loop is pure gather+add.
// MODE 0: out = relu(dn*sum + b) -> bf16 hi/lo (layer-2 GEMM input)
// MODE 1: CORAL head: logits[node][0..3] = dot(relu(...), wfc) + thb
template <int MODE>
__global__ __launch_bounds__(256) void agg_kernel(
    const float* __restrict__ H, const int* __restrict__ row_ptr,
    const int* __restrict__ cnt, const int* __restrict__ ssrc,
    const float* __restrict__ dis, const float* __restrict__ bias,
    u16* __restrict__ Ohi, u16* __restrict__ Olo,
    float* __restrict__ out, const float* __restrict__ wfc,
    const float* __restrict__ thb, int n) {
    const int wave = threadIdx.x >> 6, lane = threadIdx.x & 63;
    const int node = blockIdx.x * 4 + wave;
    if (node >= n) return;
    const float2* __restrict__ Hv = (const float2*)H;
    const int beg = row_ptr[node];
    const int end = beg + cnt[node];
    float2 hv = Hv[(size_t)node * 64 + lane];
    float ax = hv.x, ay = hv.y;
    int j = beg;
    for (; j + 8 <= end; j += 8) {
        int s[8];
#pragma unroll
        for (int u = 0; u < 8; ++u) s[u] = ssrc[j + u];
        float2 m[8];
#pragma unroll
        for (int u = 0; u < 8; ++u) m[u] = Hv[(size_t)s[u] * 64 + lane];
#pragma unroll
        for (int u = 0; u < 8; ++u) { ax += m[u].x; ay += m[u].y; }
    }
    for (; j + 2 <= end; j += 2) {
        const int s0 = ssrc[j], s1 = ssrc[j + 1];
        float2 m0 = Hv[(size_t)s0 * 64 + lane];
        float2 m1 = Hv[(size_t)s1 * 64 + lane];
        ax += m0.x + m1.x;
        ay += m0.y + m1.y;
    }
    if (j < end) {
        const int s = ssrc[j];
        float2 m = Hv[(size_t)s * 64 + lane];
        ax += m.x; ay += m.y;
    }
    const float dn = dis[node];
    const float2 bv = ((const float2*)bias)[lane];
    const float o0 = fmaxf(fmaf(dn, ax, bv.x), 0.f);
    const float o1 = fmaxf(fmaf(dn, ay, bv.y), 0.f);
    if (MODE == 0) {
        ushort2 h, l;
        h.x = f2bf(o0); l.x = f2bf(o0 - bf2f(h.x));
        h.y = f2bf(o1); l.y = f2bf(o1 - bf2f(h.y));
        ((ushort2*)Ohi)[(size_t)node * 64 + lane] = h;
        ((ushort2*)Olo)[(size_t)node * 64 + lane] = l;
    } else {
        const float2 wv = ((const float2*)wfc)[lane];
        float part = fmaf(o0, wv.x, o1 * wv.y);
#pragma unroll
        for (int m_ = 32; m_ >= 1; m_ >>= 1) part += __shfl_xor(part, m_, 64);
        if (lane < 4) out[(size_t)node * 4 + lane] = part + thb[lane];
    }
}

extern "C" void kernel_launch(void* const* d_in, const int* in_sizes, int n_in,
                              void* d_out, int out_size, void* d_ws, size_t ws_size,
                              hipStream_t stream) {
    const float* x   = (const float*)d_in[0];
    const int*   ei  = (const int*)d_in[1];
    const float* W1  = (const float*)d_in[2];
    const float* b1  = (const float*)d_in[3];
    const float* W2  = (const float*)d_in[4];
    const float* b2  = (const float*)d_in[5];
    const float* wfc = (const float*)d_in[6];
    const float* thb = (const float*)d_in[7];
    const int N = in_sizes[0] / FEAT;
    const int E = in_sizes[1] / 2;
    float* out = (float*)d_out;

    char* w = (char*)d_ws;
    int*   flag = (int*)w;                        // [1]
    int*   bsum = (int*)(w + 256);                // [<=256]
    int*   deg  = (int*)(w + 2048);               // [N]
    int*   rowp = deg + N;                        // [N]
    int*   curs = rowp + N;                       // [N]
    float* dis  = (float*)(curs + N);             // [N]
    int*   ssrc = (int*)(dis + N);                // [E]
    size_t off  = (((char*)(ssrc + E)) - w + 511) & ~(size_t)511;
    u16*   w1h  = (u16*)(w + off);                // [128*128]
    u16*   w1l  = w1h + 16384;
    u16*   w2h  = w1l + 16384;
    u16*   w2l  = w2h + 16384;
    u16*   xhi  = w2l + 16384;                    // [N*128] (aliased: h1 hi)
    u16*   xlo  = xhi + (size_t)N * FEAT;         // [N*128] (aliased: h1 lo)
    size_t off2 = (((char*)(xlo + (size_t)N * FEAT)) - w + 511) & ~(size_t)511;
    float* g    = (float*)(w + off2);             // [N*128] GEMM out / agg in

    hipMemsetAsync(deg, 0, (size_t)N * 4, stream);
    detect_mode<<<1, 64, 0, stream>>>(ei, flag);
    count_deg<<<(E + 255) / 256, 256, 0, stream>>>(ei, flag, deg, E);
    calc_dis<<<(N + 255) / 256, 256, 0, stream>>>(deg, dis, N);
    const int NB = (N + 2047) / 2048;
    scan1<<<NB, 256, 0, stream>>>(deg, rowp, bsum, N);
    scan2<<<1, 256, 0, stream>>>(bsum, NB);
    scan3<<<(N + 255) / 256, 256, 0, stream>>>(rowp, curs, bsum, N);
    fill_sorted<<<(E + 255) / 256, 256, 0, stream>>>(ei, flag, curs, ssrc, E);

    conv_x<<<(N * FEAT / 4 + 255) / 256, 256, 0, stream>>>(x, xhi, xlo, N * FEAT / 4);
    conv_w<<<64, 256, 0, stream>>>(W1, w1h, w1l);
    conv_w<<<64, 256, 0, stream>>>(W2, w2h, w2l);

    const int nt = (N + 15) / 16;
    const int gblocks = nt < 1024 ? nt : 1024;
    gemm_mfma<<<gblocks, 256, 0, stream>>>(xhi, xlo, w1h, w1l, dis, g, N, nt);
    agg_kernel<0><<<(N + 3) / 4, 256, 0, stream>>>(g, rowp, deg, ssrc, dis, b1,
                                                   xhi, xlo, nullptr, nullptr, nullptr, N);
    gemm_mfma<<<gblocks, 256, 0, stream>>>(xhi, xlo, w2h, w2l, dis, g, N, nt);
    agg_kernel<1><<<(N + 3) / 4, 256, 0, stream>>>(g, rowp, deg, ssrc, dis, b2,
                                                   nullptr, nullptr, out, wfc, thb, N);
}

// Round 5
// 567.933 us; speedup vs baseline: 1.7895x; 1.0857x over previous
//
#include <hip/hip_runtime.h>
#include <hip/hip_bf16.h>

// 2-layer GCN + CORAL head, MFMA edition, XCD-partitioned sort.
//  - split-bf16 (hi/lo) MFMA GEMM: x@W = (xh+xl)@(wh+wl), 4 products, fp32 acc
//    layer-1 GEMM converts fp32 x -> hi/lo in-register (no conv_x pass)
//  - GEMM epilogue pre-scales row r by deg_inv_sqrt[r]  => agg loop is pure add
//  - counting sort partitioned by dst range (8 XCD slices): scatter writes stay
//    in one XCD's L2 slice -> kills the 16x write amplification seen in r4
//  - pull-model aggregation over CSR (atomic-free), unroll x8
//  - layer-1 agg fuses relu + bf16 hi/lo conversion; layer-2 agg fuses CORAL head

#define FEAT 128
#define CHUNK 4096
typedef unsigned short u16;
typedef __attribute__((ext_vector_type(8))) short bf16x8;
typedef __attribute__((ext_vector_type(4))) float f32x4;
#define MFMA16 __builtin_amdgcn_mfma_f32_16x16x32_bf16

__device__ inline u16 f2bf(float f) {
    __hip_bfloat16 b = __float2bfloat16(f);
    return __builtin_bit_cast(u16, b);
}
__device__ inline float bf2f(u16 u) {
    __hip_bfloat16 b = __builtin_bit_cast(__hip_bfloat16, u);
    return __bfloat162float(b);
}

// ---------------- mode detect (int64 vs int32 edge_index) ----------------
__global__ void detect_mode(const int* __restrict__ p, int* __restrict__ flag) {
    int t = threadIdx.x;
    int v = p[2 * t + 1];
    unsigned long long b = __ballot(v != 0);
    if (t == 0) flag[0] = (b == 0ull) ? 1 : 0;
}

// ---------------- degree histogram, dst-partitioned (8 XCD slices) ----------
__global__ __launch_bounds__(256) void count_deg(const int* __restrict__ p,
                                                 const int* __restrict__ flag,
                                                 int* __restrict__ cnt, int E,
                                                 int nper) {
    const int part = blockIdx.x & 7;
    const int lo = part * nper, hi = lo + nper;
    const int i0 = (int)(blockIdx.x >> 3) * CHUNK;
    const int iend = min(i0 + CHUNK, E);
    const int m = flag[0];
    for (int i = i0 + threadIdx.x; i < iend; i += 256) {
        int d = m ? p[2 * ((size_t)E + i)] : p[(size_t)E + i];
        if (d >= lo && d < hi) atomicAdd(&cnt[d], 1);
    }
}

__global__ void calc_dis(const int* __restrict__ cnt, float* __restrict__ dis, int n) {
    int i = blockIdx.x * blockDim.x + threadIdx.x;
    if (i < n) dis[i] = 1.0f / sqrtf((float)cnt[i] + 1.0f);
}

// ---------------- 3-kernel exclusive scan ----------------
__global__ void scan1(const int* __restrict__ cnt, int* __restrict__ out,
                      int* __restrict__ bsum, int n) {
    __shared__ int tmp[256];
    int base = blockIdx.x * 2048;
    int idx = base + threadIdx.x * 8;
    int v[8]; int s = 0;
#pragma unroll
    for (int i = 0; i < 8; ++i) { int id = idx + i; v[i] = (id < n) ? cnt[id] : 0; s += v[i]; }
    tmp[threadIdx.x] = s;
    __syncthreads();
    for (int off = 1; off < 256; off <<= 1) {
        int t = (threadIdx.x >= (unsigned)off) ? tmp[threadIdx.x - off] : 0;
        __syncthreads();
        tmp[threadIdx.x] += t;
        __syncthreads();
    }
    int excl = (threadIdx.x == 0) ? 0 : tmp[threadIdx.x - 1];
    if (threadIdx.x == 255) bsum[blockIdx.x] = tmp[255];
    int run = excl;
#pragma unroll
    for (int i = 0; i < 8; ++i) { int id = idx + i; if (id < n) out[id] = run; run += v[i]; }
}

__global__ void scan2(int* __restrict__ bsum, int nb) {
    __shared__ int tmp[256];
    int v = (threadIdx.x < (unsigned)nb) ? bsum[threadIdx.x] : 0;
    tmp[threadIdx.x] = v;
    __syncthreads();
    for (int off = 1; off < 256; off <<= 1) {
        int t = (threadIdx.x >= (unsigned)off) ? tmp[threadIdx.x - off] : 0;
        __syncthreads();
        tmp[threadIdx.x] += t;
        __syncthreads();
    }
    int excl = (threadIdx.x == 0) ? 0 : tmp[threadIdx.x - 1];
    if (threadIdx.x < (unsigned)nb) bsum[threadIdx.x] = excl;
}

__global__ void scan3(int* __restrict__ out, int* __restrict__ cursor,
                      const int* __restrict__ bsum, int n) {
    int i = blockIdx.x * blockDim.x + threadIdx.x;
    if (i < n) {
        int v = out[i] + bsum[i >> 11];
        out[i] = v;
        cursor[i] = v;
    }
}

// ---------------- counting-sort fill, dst-partitioned (8 XCD slices) ---------
__global__ __launch_bounds__(256) void fill_sorted(const int* __restrict__ p,
                                                   const int* __restrict__ flag,
                                                   int* __restrict__ cursor,
                                                   int* __restrict__ ssrc, int E,
                                                   int nper) {
    const int part = blockIdx.x & 7;
    const int lo = part * nper, hi = lo + nper;
    const int i0 = (int)(blockIdx.x >> 3) * CHUNK;
    const int iend = min(i0 + CHUNK, E);
    const int m = flag[0];
    for (int i = i0 + threadIdx.x; i < iend; i += 256) {
        int d = m ? p[2 * ((size_t)E + i)] : p[(size_t)E + i];
        if (d >= lo && d < hi) {
            int s = m ? p[2 * (size_t)i] : p[(size_t)i];
            int pos = atomicAdd(&cursor[d], 1);
            ssrc[pos] = s;
        }
    }
}

// W [k][col] fp32 -> transposed bf16 hi/lo Wt[col][k]
__global__ void conv_w(const float* __restrict__ W, u16* __restrict__ th,
                       u16* __restrict__ tl) {
    int idx = blockIdx.x * 256 + threadIdx.x;   // 16384
    int k = idx >> 7, col = idx & 127;
    float v = W[idx];
    u16 h = f2bf(v);
    u16 l = f2bf(v - bf2f(h));
    th[col * 128 + k] = h;
    tl[col * 128 + k] = l;
}

// ---------------- MFMA GEMM: Y[r][c] = dis[r] * sum_k X[r][k] W[k][c] ----------
// FP32IN: X fp32 [N][128], hi/lo split in-register. Else bf16 hi/lo arrays.
// W transposed bf16 hi/lo [col][128]. Block = 4 waves; wave owns 32 cols
// (B frags resident); grid-strides over 16-row tiles.
template <bool FP32IN>
__global__ __launch_bounds__(256) void gemm_mfma(
    const float* __restrict__ Xf,
    const u16* __restrict__ Xhi, const u16* __restrict__ Xlo,
    const u16* __restrict__ Whi, const u16* __restrict__ Wlo,
    const float* __restrict__ dis, float* __restrict__ Y, int n, int nt) {
    const int wave = threadIdx.x >> 6, lane = threadIdx.x & 63;
    const int l15 = lane & 15, hi4 = lane >> 4;

    bf16x8 bh[2][4], bl[2][4];
#pragma unroll
    for (int ct = 0; ct < 2; ++ct) {
        const int col = wave * 32 + ct * 16 + l15;
#pragma unroll
        for (int j = 0; j < 4; ++j) {
            const int off = col * 128 + j * 32 + hi4 * 8;
            bh[ct][j] = *(const bf16x8*)(Whi + off);
            bl[ct][j] = *(const bf16x8*)(Wlo + off);
        }
    }

    for (int rt = blockIdx.x; rt < nt; rt += gridDim.x) {
        const int r0 = rt * 16;
        const int row = min(r0 + l15, n - 1);
        bf16x8 ah[4], al[4];
        if (FP32IN) {
            const float* Xr = Xf + (size_t)row * FEAT;
#pragma unroll
            for (int j = 0; j < 4; ++j) {
                float4 v0 = *(const float4*)(Xr + j * 32 + hi4 * 8);
                float4 v1 = *(const float4*)(Xr + j * 32 + hi4 * 8 + 4);
                float vv[8] = {v0.x, v0.y, v0.z, v0.w, v1.x, v1.y, v1.z, v1.w};
                bf16x8 h8, l8;
#pragma unroll
                for (int e = 0; e < 8; ++e) {
                    u16 h = f2bf(vv[e]);
                    u16 l = f2bf(vv[e] - bf2f(h));
                    h8[e] = (short)h; l8[e] = (short)l;
                }
                ah[j] = h8; al[j] = l8;
            }
        } else {
#pragma unroll
            for (int j = 0; j < 4; ++j) {
                const size_t off = (size_t)row * FEAT + j * 32 + hi4 * 8;
                ah[j] = *(const bf16x8*)(Xhi + off);
                al[j] = *(const bf16x8*)(Xlo + off);
            }
        }
#pragma unroll
        for (int ct = 0; ct < 2; ++ct) {
            f32x4 a = {0.f, 0.f, 0.f, 0.f};
#pragma unroll
            for (int j = 0; j < 4; ++j) {
                a = MFMA16(ah[j], bh[ct][j], a, 0, 0, 0);
                a = MFMA16(al[j], bh[ct][j], a, 0, 0, 0);
                a = MFMA16(ah[j], bl[ct][j], a, 0, 0, 0);
                a = MFMA16(al[j], bl[ct][j], a, 0, 0, 0);
            }
            const int c0 = wave * 32 + ct * 16 + l15;
#pragma unroll
            for (int q = 0; q < 4; ++q) {
                const int r = r0 + hi4 * 4 + q;
                if (r < n) Y[(size_t)r * FEAT + c0] = a[q] * dis[r];
            }
        }
    }
}

// ---------------- pull aggregate ----------------
// H rows are pre-scaled by dis[row]; inner loop is pure gather+add.
// MODE 0: out = relu(dn*sum + b) -> bf16 hi/lo (layer-2 GEMM input)
// MODE 1: CORAL head: logits[node][0..3] = dot(relu(...), wfc) + thb
template <int MODE>
__global__ __launch_bounds__(256) void agg_kernel(
    const float* __restrict__ H, const int* __restrict__ row_ptr,
    const int* __restrict__ cnt, const int* __restrict__ ssrc,
    const float* __restrict__ dis, const float* __restrict__ bias,
    u16* __restrict__ Ohi, u16* __restrict__ Olo,
    float* __restrict__ out, const float* __restrict__ wfc,
    const float* __restrict__ thb, int n) {
    const int wave = threadIdx.x >> 6, lane = threadIdx.x & 63;
    const int node = blockIdx.x * 4 + wave;
    if (node >= n) return;
    const float2* __restrict__ Hv = (const float2*)H;
    const int beg = row_ptr[node];
    const int end = beg + cnt[node];
    float2 hv = Hv[(size_t)node * 64 + lane];
    float ax = hv.x, ay = hv.y;
    int j = beg;
    for (; j + 8 <= end; j += 8) {
        int s[8];
#pragma unroll
        for (int u = 0; u < 8; ++u) s[u] = ssrc[j + u];
        float2 m[8];
#pragma unroll
        for (int u = 0; u < 8; ++u) m[u] = Hv[(size_t)s[u] * 64 + lane];
#pragma unroll
        for (int u = 0; u < 8; ++u) { ax += m[u].x; ay += m[u].y; }
    }
    for (; j + 2 <= end; j += 2) {
        const int s0 = ssrc[j], s1 = ssrc[j + 1];
        float2 m0 = Hv[(size_t)s0 * 64 + lane];
        float2 m1 = Hv[(size_t)s1 * 64 + lane];
        ax += m0.x + m1.x;
        ay += m0.y + m1.y;
    }
    if (j < end) {
        const int s = ssrc[j];
        float2 m = Hv[(size_t)s * 64 + lane];
        ax += m.x; ay += m.y;
    }
    const float dn = dis[node];
    const float2 bv = ((const float2*)bias)[lane];
    const float o0 = fmaxf(fmaf(dn, ax, bv.x), 0.f);
    const float o1 = fmaxf(fmaf(dn, ay, bv.y), 0.f);
    if (MODE == 0) {
        ushort2 h, l;
        h.x = f2bf(o0); l.x = f2bf(o0 - bf2f(h.x));
        h.y = f2bf(o1); l.y = f2bf(o1 - bf2f(h.y));
        ((ushort2*)Ohi)[(size_t)node * 64 + lane] = h;
        ((ushort2*)Olo)[(size_t)node * 64 + lane] = l;
    } else {
        const float2 wv = ((const float2*)wfc)[lane];
        float part = fmaf(o0, wv.x, o1 * wv.y);
#pragma unroll
        for (int m_ = 32; m_ >= 1; m_ >>= 1) part += __shfl_xor(part, m_, 64);
        if (lane < 4) out[(size_t)node * 4 + lane] = part + thb[lane];
    }
}

extern "C" void kernel_launch(void* const* d_in, const int* in_sizes, int n_in,
                              void* d_out, int out_size, void* d_ws, size_t ws_size,
                              hipStream_t stream) {
    const float* x   = (const float*)d_in[0];
    const int*   ei  = (const int*)d_in[1];
    const float* W1  = (const float*)d_in[2];
    const float* b1  = (const float*)d_in[3];
    const float* W2  = (const float*)d_in[4];
    const float* b2  = (const float*)d_in[5];
    const float* wfc = (const float*)d_in[6];
    const float* thb = (const float*)d_in[7];
    const int N = in_sizes[0] / FEAT;
    const int E = in_sizes[1] / 2;
    float* out = (float*)d_out;

    char* w = (char*)d_ws;
    int*   flag = (int*)w;                        // [1]
    int*   bsum = (int*)(w + 256);                // [<=256]
    int*   deg  = (int*)(w + 2048);               // [N]
    int*   rowp = deg + N;                        // [N]
    int*   curs = rowp + N;                       // [N]
    float* dis  = (float*)(curs + N);             // [N]
    int*   ssrc = (int*)(dis + N);                // [E]
    size_t off  = (((char*)(ssrc + E)) - w + 511) & ~(size_t)511;
    u16*   w1h  = (u16*)(w + off);                // [128*128]
    u16*   w1l  = w1h + 16384;
    u16*   w2h  = w1l + 16384;
    u16*   w2l  = w2h + 16384;
    u16*   xhi  = w2l + 16384;                    // [N*128] h1 hi (bf16)
    u16*   xlo  = xhi + (size_t)N * FEAT;         // [N*128] h1 lo (bf16)
    size_t off2 = (((char*)(xlo + (size_t)N * FEAT)) - w + 511) & ~(size_t)511;
    float* g    = (float*)(w + off2);             // [N*128] GEMM out / agg in

    const int nper = (N + 7) / 8;                 // dst-partition width
    const int nch  = (E + CHUNK - 1) / CHUNK;     // edge chunks per partition

    hipMemsetAsync(deg, 0, (size_t)N * 4, stream);
    detect_mode<<<1, 64, 0, stream>>>(ei, flag);
    count_deg<<<nch * 8, 256, 0, stream>>>(ei, flag, deg, E, nper);
    calc_dis<<<(N + 255) / 256, 256, 0, stream>>>(deg, dis, N);
    const int NB = (N + 2047) / 2048;
    scan1<<<NB, 256, 0, stream>>>(deg, rowp, bsum, N);
    scan2<<<1, 256, 0, stream>>>(bsum, NB);
    scan3<<<(N + 255) / 256, 256, 0, stream>>>(rowp, curs, bsum, N);
    fill_sorted<<<nch * 8, 256, 0, stream>>>(ei, flag, curs, ssrc, E, nper);

    conv_w<<<64, 256, 0, stream>>>(W1, w1h, w1l);
    conv_w<<<64, 256, 0, stream>>>(W2, w2h, w2l);

    const int nt = (N + 15) / 16;
    const int gblocks = nt < 1024 ? nt : 1024;
    gemm_mfma<true><<<gblocks, 256, 0, stream>>>(x, nullptr, nullptr, w1h, w1l,
                                                 dis, g, N, nt);
    agg_kernel<0><<<(N + 3) / 4, 256, 0, stream>>>(g, rowp, deg, ssrc, dis, b1,
                                                   xhi, xlo, nullptr, nullptr, nullptr, N);
    gemm_mfma<false><<<gblocks, 256, 0, stream>>>(nullptr, xhi, xlo, w2h, w2l,
                                                  dis, g, N, nt);
    agg_kernel<1><<<(N + 3) / 4, 256, 0, stream>>>(g, rowp, deg, ssrc, dis, b2,
                                                   nullptr, nullptr, out, wfc, thb, N);
}

// Round 6
// 471.514 us; speedup vs baseline: 2.1554x; 1.2045x over previous
//
#include <hip/hip_runtime.h>
#include <hip/hip_bf16.h>

// 2-layer GCN + CORAL head, MFMA + bf16-gather edition.
//  - split-bf16 (hi/lo) MFMA GEMM; epilogue scales row r by deg_inv_sqrt[r]
//    and stores g as ONE bf16 plane (256 B rows) -> halves agg gather traffic
//  - agg gathers u32 (2 bf16 feats)/lane, accumulates fp32
//  - counting sort: simple atomic histogram; dst-partitioned fill (XCD-local
//    ssrc writes); no scan3/cursor (pos = bsum + fetch_add(rowp))
//  - int64-vs-int32 edge layout detected per-block (no extra dispatch)
//  - layer-1 agg fuses relu + bf16 hi/lo conversion; layer-2 agg fuses CORAL head

#define FEAT 128
#define CHUNK 4096
typedef unsigned short u16;
typedef unsigned int u32;
typedef __attribute__((ext_vector_type(8))) short bf16x8;
typedef __attribute__((ext_vector_type(4))) float f32x4;
#define MFMA16 __builtin_amdgcn_mfma_f32_16x16x32_bf16

__device__ inline u16 f2bf(float f) {
    __hip_bfloat16 b = __float2bfloat16(f);
    return __builtin_bit_cast(u16, b);
}
__device__ inline float bf2f(u16 u) {
    __hip_bfloat16 b = __builtin_bit_cast(__hip_bfloat16, u);
    return __bfloat162float(b);
}

// ---------------- degree histogram (simple; detect inlined) ----------------
__global__ __launch_bounds__(256) void count_deg(const int* __restrict__ p,
                                                 int* __restrict__ cnt, int E) {
    __shared__ int sflag;
    if (threadIdx.x < 64) {
        int v = p[2 * (int)threadIdx.x + 1];
        unsigned long long b = __ballot(v != 0);
        if (threadIdx.x == 0) sflag = (b == 0ull) ? 1 : 0;
    }
    __syncthreads();
    const int m = sflag;
    int i = blockIdx.x * 256 + threadIdx.x;
    if (i >= E) return;
    int d = m ? p[2 * ((size_t)E + i)] : p[(size_t)E + i];
    atomicAdd(&cnt[d], 1);
}

// ---------------- scan1: block-exclusive scan + fused deg_inv_sqrt ----------
__global__ void scan1(const int* __restrict__ cnt, int* __restrict__ out,
                      int* __restrict__ bsum, float* __restrict__ dis, int n) {
    __shared__ int tmp[256];
    int base = blockIdx.x * 2048;
    int idx = base + threadIdx.x * 8;
    int v[8]; int s = 0;
#pragma unroll
    for (int i = 0; i < 8; ++i) {
        int id = idx + i;
        v[i] = (id < n) ? cnt[id] : 0;
        s += v[i];
        if (id < n) dis[id] = 1.0f / sqrtf((float)v[i] + 1.0f);
    }
    tmp[threadIdx.x] = s;
    __syncthreads();
    for (int off = 1; off < 256; off <<= 1) {
        int t = (threadIdx.x >= (unsigned)off) ? tmp[threadIdx.x - off] : 0;
        __syncthreads();
        tmp[threadIdx.x] += t;
        __syncthreads();
    }
    int excl = (threadIdx.x == 0) ? 0 : tmp[threadIdx.x - 1];
    if (threadIdx.x == 255) bsum[blockIdx.x] = tmp[255];
    int run = excl;
#pragma unroll
    for (int i = 0; i < 8; ++i) { int id = idx + i; if (id < n) out[id] = run; run += v[i]; }
}

__global__ void scan2(int* __restrict__ bsum, int nb) {
    __shared__ int tmp[256];
    int v = (threadIdx.x < (unsigned)nb) ? bsum[threadIdx.x] : 0;
    tmp[threadIdx.x] = v;
    __syncthreads();
    for (int off = 1; off < 256; off <<= 1) {
        int t = (threadIdx.x >= (unsigned)off) ? tmp[threadIdx.x - off] : 0;
        __syncthreads();
        tmp[threadIdx.x] += t;
        __syncthreads();
    }
    int excl = (threadIdx.x == 0) ? 0 : tmp[threadIdx.x - 1];
    if (threadIdx.x < (unsigned)nb) bsum[threadIdx.x] = excl;
}

// ---------------- counting-sort fill, dst-partitioned (8 XCD slices) ---------
// pos = bsum[d>>11] + fetch_add(rowp[d]). After this kernel:
//   rowp[d] = local_excl[d] + cnt[d]  =>  beg(d) = bsum[d>>11] + rowp[d] - cnt[d]
__global__ __launch_bounds__(256) void fill_sorted(const int* __restrict__ p,
                                                   int* __restrict__ rowp,
                                                   const int* __restrict__ bsum,
                                                   int* __restrict__ ssrc, int E,
                                                   int nper) {
    __shared__ int sflag;
    if (threadIdx.x < 64) {
        int v = p[2 * (int)threadIdx.x + 1];
        unsigned long long b = __ballot(v != 0);
        if (threadIdx.x == 0) sflag = (b == 0ull) ? 1 : 0;
    }
    __syncthreads();
    const int m = sflag;
    const int part = blockIdx.x & 7;
    const int lo = part * nper, hi = lo + nper;
    const int i0 = (int)(blockIdx.x >> 3) * CHUNK;
    const int iend = min(i0 + CHUNK, E);
    for (int i = i0 + threadIdx.x; i < iend; i += 256) {
        int d = m ? p[2 * ((size_t)E + i)] : p[(size_t)E + i];
        if (d >= lo && d < hi) {
            int s = m ? p[2 * (size_t)i] : p[(size_t)i];
            int pos = bsum[d >> 11] + atomicAdd(&rowp[d], 1);
            ssrc[pos] = s;
        }
    }
}

// W [k][col] fp32 -> transposed bf16 hi/lo Wt[col][k]
__global__ void conv_w(const float* __restrict__ W, u16* __restrict__ th,
                       u16* __restrict__ tl) {
    int idx = blockIdx.x * 256 + threadIdx.x;   // 16384
    int k = idx >> 7, col = idx & 127;
    float v = W[idx];
    u16 h = f2bf(v);
    u16 l = f2bf(v - bf2f(h));
    th[col * 128 + k] = h;
    tl[col * 128 + k] = l;
}

// ---------------- MFMA GEMM: G[r][c] = bf16( dis[r] * sum_k X[r][k] W[k][c] )
// FP32IN: X fp32, hi/lo split in-register. Else bf16 hi/lo planes.
// W transposed bf16 hi/lo [col][128]. Block = 4 waves; wave owns 32 cols.
template <bool FP32IN>
__global__ __launch_bounds__(256) void gemm_mfma(
    const float* __restrict__ Xf,
    const u16* __restrict__ Xhi, const u16* __restrict__ Xlo,
    const u16* __restrict__ Whi, const u16* __restrict__ Wlo,
    const float* __restrict__ dis, u16* __restrict__ G, int n, int nt) {
    const int wave = threadIdx.x >> 6, lane = threadIdx.x & 63;
    const int l15 = lane & 15, hi4 = lane >> 4;

    bf16x8 bh[2][4], bl[2][4];
#pragma unroll
    for (int ct = 0; ct < 2; ++ct) {
        const int col = wave * 32 + ct * 16 + l15;
#pragma unroll
        for (int j = 0; j < 4; ++j) {
            const int off = col * 128 + j * 32 + hi4 * 8;
            bh[ct][j] = *(const bf16x8*)(Whi + off);
            bl[ct][j] = *(const bf16x8*)(Wlo + off);
        }
    }

    for (int rt = blockIdx.x; rt < nt; rt += gridDim.x) {
        const int r0 = rt * 16;
        const int row = min(r0 + l15, n - 1);
        bf16x8 ah[4], al[4];
        if (FP32IN) {
            const float* Xr = Xf + (size_t)row * FEAT;
#pragma unroll
            for (int j = 0; j < 4; ++j) {
                float4 v0 = *(const float4*)(Xr + j * 32 + hi4 * 8);
                float4 v1 = *(const float4*)(Xr + j * 32 + hi4 * 8 + 4);
                float vv[8] = {v0.x, v0.y, v0.z, v0.w, v1.x, v1.y, v1.z, v1.w};
                bf16x8 h8, l8;
#pragma unroll
                for (int e = 0; e < 8; ++e) {
                    u16 h = f2bf(vv[e]);
                    u16 l = f2bf(vv[e] - bf2f(h));
                    h8[e] = (short)h; l8[e] = (short)l;
                }
                ah[j] = h8; al[j] = l8;
            }
        } else {
#pragma unroll
            for (int j = 0; j < 4; ++j) {
                const size_t off = (size_t)row * FEAT + j * 32 + hi4 * 8;
                ah[j] = *(const bf16x8*)(Xhi + off);
                al[j] = *(const bf16x8*)(Xlo + off);
            }
        }
        float dr[4];
#pragma unroll
        for (int q = 0; q < 4; ++q) {
            const int r = r0 + hi4 * 4 + q;
            dr[q] = (r < n) ? dis[r] : 0.f;
        }
#pragma unroll
        for (int ct = 0; ct < 2; ++ct) {
            f32x4 a = {0.f, 0.f, 0.f, 0.f};
#pragma unroll
            for (int j = 0; j < 4; ++j) {
                a = MFMA16(ah[j], bh[ct][j], a, 0, 0, 0);
                a = MFMA16(al[j], bh[ct][j], a, 0, 0, 0);
                a = MFMA16(ah[j], bl[ct][j], a, 0, 0, 0);
                a = MFMA16(al[j], bl[ct][j], a, 0, 0, 0);
            }
            const int c0 = wave * 32 + ct * 16 + l15;
#pragma unroll
            for (int q = 0; q < 4; ++q) {
                const int r = r0 + hi4 * 4 + q;
                if (r < n) G[(size_t)r * FEAT + c0] = f2bf(a[q] * dr[q]);
            }
        }
    }
}

// ---------------- pull aggregate over bf16 plane ----------------
// G rows pre-scaled by dis[row]; one u32 (2 bf16 feats)/lane per gathered row.
// MODE 0: relu(dn*sum + b) -> bf16 hi/lo planes (layer-2 GEMM input)
// MODE 1: CORAL head: out[node][0..3] = dot(relu(...), wfc) + thb
template <int MODE>
__global__ __launch_bounds__(256) void agg_kernel(
    const u16* __restrict__ G, const int* __restrict__ rowp,
    const int* __restrict__ cnt, const int* __restrict__ bsum,
    const int* __restrict__ ssrc, const float* __restrict__ dis,
    const float* __restrict__ bias,
    u16* __restrict__ Ohi, u16* __restrict__ Olo,
    float* __restrict__ out, const float* __restrict__ wfc,
    const float* __restrict__ thb, int n) {
    const int wave = threadIdx.x >> 6, lane = threadIdx.x & 63;
    const int node = blockIdx.x * 4 + wave;
    if (node >= n) return;
    const u32* __restrict__ Gv = (const u32*)G;
    const int c = cnt[node];
    const int beg = bsum[node >> 11] + rowp[node] - c;
    const int end = beg + c;
    u32 uself = Gv[(size_t)node * 64 + lane];
    float ax = __uint_as_float(uself << 16);
    float ay = __uint_as_float(uself & 0xffff0000u);
    int j = beg;
    for (; j + 8 <= end; j += 8) {
        int s[8];
#pragma unroll
        for (int u = 0; u < 8; ++u) s[u] = ssrc[j + u];
        u32 m[8];
#pragma unroll
        for (int u = 0; u < 8; ++u) m[u] = Gv[(size_t)s[u] * 64 + lane];
#pragma unroll
        for (int u = 0; u < 8; ++u) {
            ax += __uint_as_float(m[u] << 16);
            ay += __uint_as_float(m[u] & 0xffff0000u);
        }
    }
    for (; j < end; ++j) {
        const int s = ssrc[j];
        u32 m = Gv[(size_t)s * 64 + lane];
        ax += __uint_as_float(m << 16);
        ay += __uint_as_float(m & 0xffff0000u);
    }
    const float dn = dis[node];
    const float2 bv = ((const float2*)bias)[lane];
    const float o0 = fmaxf(fmaf(dn, ax, bv.x), 0.f);
    const float o1 = fmaxf(fmaf(dn, ay, bv.y), 0.f);
    if (MODE == 0) {
        ushort2 h, l;
        h.x = f2bf(o0); l.x = f2bf(o0 - bf2f(h.x));
        h.y = f2bf(o1); l.y = f2bf(o1 - bf2f(h.y));
        ((ushort2*)Ohi)[(size_t)node * 64 + lane] = h;
        ((ushort2*)Olo)[(size_t)node * 64 + lane] = l;
    } else {
        const float2 wv = ((const float2*)wfc)[lane];
        float part = fmaf(o0, wv.x, o1 * wv.y);
#pragma unroll
        for (int m_ = 32; m_ >= 1; m_ >>= 1) part += __shfl_xor(part, m_, 64);
        if (lane < 4) out[(size_t)node * 4 + lane] = part + thb[lane];
    }
}

extern "C" void kernel_launch(void* const* d_in, const int* in_sizes, int n_in,
                              void* d_out, int out_size, void* d_ws, size_t ws_size,
                              hipStream_t stream) {
    const float* x   = (const float*)d_in[0];
    const int*   ei  = (const int*)d_in[1];
    const float* W1  = (const float*)d_in[2];
    const float* b1  = (const float*)d_in[3];
    const float* W2  = (const float*)d_in[4];
    const float* b2  = (const float*)d_in[5];
    const float* wfc = (const float*)d_in[6];
    const float* thb = (const float*)d_in[7];
    const int N = in_sizes[0] / FEAT;
    const int E = in_sizes[1] / 2;
    float* out = (float*)d_out;

    char* w = (char*)d_ws;
    int*   bsum = (int*)w;                        // [<=256]
    int*   deg  = (int*)(w + 1024);               // [N]  (= cnt)
    int*   rowp = deg + N;                        // [N]
    float* dis  = (float*)(rowp + N);             // [N]
    int*   ssrc = (int*)(dis + N);                // [E]
    size_t off  = (((char*)(ssrc + E)) - w + 511) & ~(size_t)511;
    u16*   w1h  = (u16*)(w + off);                // [128*128]
    u16*   w1l  = w1h + 16384;
    u16*   w2h  = w1l + 16384;
    u16*   w2l  = w2h + 16384;
    u16*   xhi  = w2l + 16384;                    // [N*128] h1 hi (bf16)
    u16*   xlo  = xhi + (size_t)N * FEAT;         // [N*128] h1 lo (bf16)
    u16*   g    = xlo + (size_t)N * FEAT;         // [N*128] bf16 plane

    const int nper = (N + 7) / 8;                 // dst-partition width
    const int nch  = (E + CHUNK - 1) / CHUNK;     // edge chunks per partition
    const int NB   = (N + 2047) / 2048;

    hipMemsetAsync(deg, 0, (size_t)N * 4, stream);
    count_deg<<<(E + 255) / 256, 256, 0, stream>>>(ei, deg, E);
    scan1<<<NB, 256, 0, stream>>>(deg, rowp, bsum, dis, N);
    scan2<<<1, 256, 0, stream>>>(bsum, NB);
    fill_sorted<<<nch * 8, 256, 0, stream>>>(ei, rowp, bsum, ssrc, E, nper);

    conv_w<<<64, 256, 0, stream>>>(W1, w1h, w1l);
    conv_w<<<64, 256, 0, stream>>>(W2, w2h, w2l);

    const int nt = (N + 15) / 16;
    const int gblocks = nt < 1024 ? nt : 1024;
    gemm_mfma<true><<<gblocks, 256, 0, stream>>>(x, nullptr, nullptr, w1h, w1l,
                                                 dis, g, N, nt);
    agg_kernel<0><<<(N + 3) / 4, 256, 0, stream>>>(g, rowp, deg, bsum, ssrc, dis, b1,
                                                   xhi, xlo, nullptr, nullptr, nullptr, N);
    gemm_mfma<false><<<gblocks, 256, 0, stream>>>(nullptr, xhi, xlo, w2h, w2l,
                                                  dis, g, N, nt);
    agg_kernel<1><<<(N + 3) / 4, 256, 0, stream>>>(g, rowp, deg, bsum, ssrc, dis, b2,
                                                   nullptr, nullptr, out, wfc, thb, N);
}